// Round 11
// baseline (247.021 us; speedup 1.0000x reference)
//
#include <hip/hip_runtime.h>
#include <hip/hip_bf16.h>

#define ALPHA 0.2f
#define EPS 1e-3f

typedef __bf16 bf16x8 __attribute__((ext_vector_type(8)));
typedef float f32x4 __attribute__((ext_vector_type(4)));

// problem dims
constexpr int B_  = 16;
constexpr int H_  = 128, W_ = 128;
constexpr int HP  = 130, WP = 130;    // padded x
constexpr int H2  = 256, W2 = 256;    // upsampled
constexpr int H2P = 258, W2P = 258;   // padded t1

// ws layout (bytes)
constexpr size_t OFF_XPAD = 0;                                   // bf16 [16][130][130][64]
constexpr size_t OFF_T1   = 34611200;                            // bf16 [16][258][258][64]
constexpr size_t OFF_PW1  = OFF_T1 + 136323072;                  // bf16 packed 576*256
constexpr size_t OFF_PW2  = OFF_PW1 + 294912;                    // bf16 packed 640*64
constexpr size_t OFF_SC   = OFF_PW2 + 81920;                     // f32 scale/shift

// async global->LDS, 16B per lane. LDS dest must be WAVE-UNIFORM (HW adds lane*16).
__device__ __forceinline__ void gload_lds16(const void* g, void* l) {
    __builtin_amdgcn_global_load_lds(
        (const __attribute__((address_space(1))) unsigned int*)g,
        (__attribute__((address_space(3))) unsigned int*)l, 16, 0, 0);
}

// ---------------- prep kernels ----------------

// pack weights in MFMA B-fragment order; block 368 computes BN scale/shift.
__global__ void pack_w(const float* W1f, const float* W2f, const float* Wuf,
                       const float* b1, const float* g1, const float* be1,
                       const float* m1, const float* v1,
                       const float* b2, const float* g2, const float* be2,
                       const float* m2, const float* v2,
                       __hip_bfloat16* pw1, __hip_bfloat16* pw2, float* sc) {
    int blk = blockIdx.x;
    int l = threadIdx.x;
    if (blk < 288) {
        int kt = blk / 16, nt = blk % 16;
        #pragma unroll
        for (int j = 0; j < 8; ++j) {
            int k = kt * 32 + (l >> 4) * 8 + j;
            int n = nt * 16 + (l & 15);
            pw1[blk * 512 + l * 8 + j] = __float2bfloat16(W1f[k * 256 + n]);
        }
    } else if (blk < 368) {
        int bi = blk - 288;
        int kt = bi / 4, nt = bi % 4;
        #pragma unroll
        for (int j = 0; j < 8; ++j) {
            int k = kt * 32 + (l >> 4) * 8 + j;
            int n = nt * 16 + (l & 15);
            float v = (k < 576) ? W2f[k * 64 + n] : Wuf[(k - 576) * 64 + n];
            pw2[bi * 512 + l * 8 + j] = __float2bfloat16(v);
        }
    } else {
        #pragma unroll
        for (int q = 0; q < 4; ++q) {
            int t = q * 64 + l;
            float s = g1[t] * rsqrtf(v1[t] + EPS);
            sc[t]       = s;
            sc[256 + t] = (b1[t] - m1[t]) * s + be1[t];
        }
        if (l < 64) {
            float s = g2[l] * rsqrtf(v2[l] + EPS);
            sc[512 + l] = s;
            sc[576 + l] = (b2[l] - m2[l]) * s + be2[l];
        }
    }
}

// fused: pad+cast x -> xp (vector bf16x8) AND zero t1 border
__global__ void prep_bufs(const float* x, __hip_bfloat16* xp,
                          __hip_bfloat16* t1, int total8, int totalb) {
    for (int e = blockIdx.x * blockDim.x + threadIdx.x; e < total8 + totalb;
         e += gridDim.x * blockDim.x) {
        if (e < total8) {
            int c8 = (e & 7) * 8;
            int t = e >> 3;
            int xx = t % WP; t /= WP;
            int yy = t % HP; t /= HP;
            int n = t;
            union { bf16x8 v; __hip_bfloat16 h[8]; } o;
            if (yy >= 1 && yy <= H_ && xx >= 1 && xx <= W_) {
                const float* src = x + ((size_t)(n * H_ + (yy - 1)) * W_ + (xx - 1)) * 64 + c8;
                float4 f0 = *(const float4*)src;
                float4 f1 = *(const float4*)(src + 4);
                o.h[0] = __float2bfloat16(f0.x); o.h[1] = __float2bfloat16(f0.y);
                o.h[2] = __float2bfloat16(f0.z); o.h[3] = __float2bfloat16(f0.w);
                o.h[4] = __float2bfloat16(f1.x); o.h[5] = __float2bfloat16(f1.y);
                o.h[6] = __float2bfloat16(f1.z); o.h[7] = __float2bfloat16(f1.w);
            } else {
                #pragma unroll
                for (int j = 0; j < 8; ++j) o.h[j] = __float2bfloat16(0.f);
            }
            *(bf16x8*)(xp + (size_t)e * 8) = o.v;
        } else {
            int eb = e - total8;            // border: 16*1028 sites x 8-ch groups
            int c8 = (eb & 7) * 8;
            int t = eb >> 3;
            int p = t % 1028;
            int n = t / 1028;
            int yy, xx;
            if (p < 258)      { yy = 0;   xx = p; }
            else if (p < 516) { yy = 257; xx = p - 258; }
            else { int p2 = p - 516; yy = 1 + (p2 >> 1); xx = (p2 & 1) ? 257 : 0; }
            union { bf16x8 v; __hip_bfloat16 h[8]; } z;
            #pragma unroll
            for (int j = 0; j < 8; ++j) z.h[j] = __float2bfloat16(0.f);
            *(bf16x8*)(t1 + ((size_t)(n * H2P + yy) * W2P + xx) * 64 + c8) = z.v;
        }
    }
}

// ---------------- GEMM1: conv1 + BN + leaky + subpixel ----------------
// R10 structure + s_setprio around MFMA clusters (T5; CU-resident blocks are
// phase-staggered -> role diversity makes setprio pay).
__global__ __launch_bounds__(256, 3)
void gemm1(const __hip_bfloat16* xp, const __hip_bfloat16* pw1,
           const float* sc, __hip_bfloat16* t1) {
    __shared__ __hip_bfloat16 lds_a[2][4608];     // 2 x 9216 B (72 px each)
    __shared__ __hip_bfloat16 lds_t1[2 * 128 * 64]; // 32768 B

    int bid = blockIdx.x;
    int b = (bid & 7) * 512 + (bid >> 3);   // XCD-chunked swizzle (4096 = 8*512)
    int n = b >> 8;
    int y = (b >> 1) & 127;
    int x0 = (b & 1) * 64;
    int w = threadIdx.x >> 6;
    int l = threadIdx.x & 63;
    int lr = l & 15, lk = l >> 4;

    const __hip_bfloat16* Bbase = pw1 + (size_t)(w * 4) * 512 + l * 8;
    f32x4 acc[4][4] = {};
    bf16x8 abuf[2][4], bbuf[3][4];

    #define STAGE1(ky_, buf_) do {                                            \
        const char* rowg = (const char*)(xp +                                 \
            ((size_t)(n * HP + y + (ky_)) * WP + x0) * 64);                   \
        for (int j = w; j < 9; j += 4) {                                      \
            int off = j * 1024 + l * 16;                                      \
            int p = off >> 7, s2 = (off >> 4) & 7;                            \
            gload_lds16(rowg + (size_t)p * 128 + ((s2 ^ (p & 7)) << 4),       \
                        (char*)lds_a[buf_] + j * 1024);                       \
        } } while (0)

    #define ALOAD1(dst, buf_, j_) do {                                        \
        int kx = (j_) >> 1;                                                   \
        int o = ((j_) & 1) * 64 + lk * 16;                                    \
        _Pragma("unroll")                                                     \
        for (int mi = 0; mi < 4; ++mi) {                                      \
            int p = mi * 16 + lr + kx;                                        \
            abuf[dst][mi] = *(const bf16x8*)((const char*)lds_a[buf_] +       \
                p * 128 + (o ^ ((p & 7) << 4)));                              \
        } } while (0)

    #define BLOAD1(s_, kt_) do {                                              \
        const __hip_bfloat16* bp = Bbase + (size_t)(kt_) * 16 * 512;          \
        _Pragma("unroll")                                                     \
        for (int ni = 0; ni < 4; ++ni)                                        \
            bbuf[s_][ni] = *(const bf16x8*)(bp + ni * 512);                   \
        } while (0)

    STAGE1(0, 0);
    BLOAD1(0, 0);
    BLOAD1(1, 1);
    BLOAD1(2, 2);
    __syncthreads();

    #pragma unroll
    for (int ky = 0; ky < 3; ++ky) {
        if (ky < 2) STAGE1(ky + 1, (ky + 1) & 1);   // in flight during compute
        ALOAD1(0, ky & 1, 0);
        #pragma unroll
        for (int j = 0; j < 6; ++j) {
            int kt = ky * 6 + j;
            if (j < 5) ALOAD1((j + 1) & 1, ky & 1, j + 1);
            __builtin_amdgcn_s_setprio(1);
            #pragma unroll
            for (int mi = 0; mi < 4; ++mi)
                #pragma unroll
                for (int ni = 0; ni < 4; ++ni)
                    acc[mi][ni] = __builtin_amdgcn_mfma_f32_16x16x32_bf16(
                        abuf[j & 1][mi], bbuf[kt % 3][ni], acc[mi][ni], 0, 0, 0);
            __builtin_amdgcn_s_setprio(0);
            if (kt + 3 < 18) BLOAD1(kt % 3, kt + 3);  // refill slot just consumed
        }
        if (ky < 2) __syncthreads();
    }
    #undef STAGE1
    #undef ALOAD1
    #undef BLOAD1

    // epilogue: BN+leaky, subpixel transpose in LDS, coalesced store
    #pragma unroll
    for (int ni = 0; ni < 4; ++ni) {
        int c = w * 64 + ni * 16 + lr;
        float s  = sc[c];
        float sh = sc[256 + c];
        int g  = c >> 2;
        int hi = (c >> 1) & 1;
        int wi = c & 1;
        #pragma unroll
        for (int mi = 0; mi < 4; ++mi) {
            #pragma unroll
            for (int r = 0; r < 4; ++r) {
                int xl = mi * 16 + lk * 4 + r;
                float v = acc[mi][ni][r] * s + sh;
                v = (v >= 0.f) ? v : ALPHA * v;
                lds_t1[(wi * 128 + 2 * xl + hi) * 64 + g] = __float2bfloat16(v);
            }
        }
    }
    __syncthreads();
    #pragma unroll
    for (int wi_ = 0; wi_ < 2; ++wi_) {
        char* dst = (char*)(t1 + ((size_t)(n * H2P + 2 * y + wi_ + 1) * W2P
                                  + 2 * x0 + 1) * 64);
        const char* src = (const char*)lds_t1 + wi_ * 16384;
        #pragma unroll
        for (int it = 0; it < 4; ++it) {
            int off = it * 4096 + threadIdx.x * 16;
            *(float4*)(dst + off) = *(const float4*)(src + off);
        }
    }
}

// ---------------- GEMM2: conv2 + BN + leaky + residual ----------------
// R10 monolithic-stage structure + s_setprio around MFMA clusters.
__global__ __launch_bounds__(256, 4)
void gemm2(const __hip_bfloat16* t1, const __hip_bfloat16* xp,
           const __hip_bfloat16* pw2, const float* sc, const float* bu,
           float* out) {
    __shared__ alignas(16) char smem[4 * 8448 + 4224];    // 4 row bufs + idn = 38016 B
    __hip_bfloat16* lds_idn = (__hip_bfloat16*)(smem + 4 * 8448);

    int bid = blockIdx.x;
    int b = (bid & 7) * 1024 + (bid >> 3);  // XCD-chunked swizzle (8192 = 8*1024)
    int n = b >> 9;
    int rem = b & 511;
    int Y0 = (rem >> 2) * 2;                // even output row pair
    int X0 = (rem & 3) * 64;
    int w = threadIdx.x >> 6;
    int l = threadIdx.x & 63;
    int lr = l & 15, lk = l >> 4;
    int ry = w >> 1;          // output row within pair
    int nh = w & 1;           // ni half: ch [nh*32, nh*32+32)

    bf16x8 abuf[2][4], bbuf[4][2];

    // stage input row r_ (padded t1 row Y0+r_), 66 px = 8448 B, into ring slot r_
    #define STAGE2(r_) do {                                                   \
        const char* rowg = (const char*)t1 +                                  \
            ((size_t)(n * H2P + Y0 + (r_)) * W2P + X0) * 128;                 \
        for (int j = w; j < 9; j += 4) {                                      \
            if (j < 8 || l < 16) {                                            \
                int off = j * 1024 + l * 16;                                  \
                int p = off >> 7, s2 = (off >> 4) & 7;                        \
                gload_lds16(rowg + (size_t)p * 128 + ((s2 ^ (p & 7)) << 4),   \
                            smem + (r_) * 8448 + j * 1024);                   \
            }                                                                 \
        } } while (0)

    #define ALOAD2(dst, rb_, j_) do {                                         \
        int kx = (j_) >> 1;                                                   \
        int o = ((j_) & 1) * 64 + lk * 16;                                    \
        _Pragma("unroll")                                                     \
        for (int mi = 0; mi < 4; ++mi) {                                      \
            int p = mi * 16 + lr + kx;                                        \
            abuf[dst][mi] = *(const bf16x8*)(smem + (rb_) * 8448 +            \
                p * 128 + (o ^ ((p & 7) << 4)));                              \
        } } while (0)

    #define BLOAD2(s_, kt_) do {                                              \
        const __hip_bfloat16* bp = pw2 +                                      \
            ((size_t)(kt_) * 4 + nh * 2) * 512 + l * 8;                       \
        _Pragma("unroll")                                                     \
        for (int ni = 0; ni < 2; ++ni)                                        \
            bbuf[s_][ni] = *(const bf16x8*)(bp + ni * 512);                   \
        } while (0)

    // ---- residual loads FIRST (oldest vmcnt slots; waves 0,1 only)
    bf16x8 pa[2], pb[2][4];
    if (w < 2) {
        #pragma unroll
        for (int kt2 = 0; kt2 < 2; ++kt2) {
            int ci0 = kt2 * 32 + lk * 8;
            int u = (X0 >> 1) + w * 16 + lr;        // low-res col (unpadded)
            pa[kt2] = *(const bf16x8*)(
                xp + ((size_t)(n * HP + (Y0 >> 1) + 1) * WP + u + 1) * 64 + ci0);
            const __hip_bfloat16* bp = pw2 + (size_t)((18 + kt2) * 4) * 512 + l * 8;
            #pragma unroll
            for (int ni = 0; ni < 4; ++ni)
                pb[kt2][ni] = *(const bf16x8*)(bp + ni * 512);
        }
    }
    STAGE2(0); STAGE2(1); STAGE2(2); STAGE2(3);
    BLOAD2(0, 0);
    BLOAD2(1, 1);
    BLOAD2(2, 2);
    BLOAD2(3, 3);

    // ---- residual 1x1 conv -> lds_idn (32 unique low-res px, shared by both rows)
    if (w < 2) {
        f32x4 aid[4] = {};
        #pragma unroll
        for (int kt2 = 0; kt2 < 2; ++kt2)
            #pragma unroll
            for (int ni = 0; ni < 4; ++ni)
                aid[ni] = __builtin_amdgcn_mfma_f32_16x16x32_bf16(
                    pa[kt2], pb[kt2][ni], aid[ni], 0, 0, 0);
        #pragma unroll
        for (int ni = 0; ni < 4; ++ni) {
            int c = ni * 16 + lr;
            float bc = bu[c];
            #pragma unroll
            for (int r = 0; r < 4; ++r) {
                int u = w * 16 + lk * 4 + r;         // local 0..31
                lds_idn[u * 66 + c] = __float2bfloat16(aid[ni][r] + bc);
            }
        }
    }
    __syncthreads();      // THE barrier: all 4 rows staged + idn ready

    // ---- barrier-free K-loop: 3 ky x 6 j x (4 mi x 2 ni) = 144 MFMAs/wave
    f32x4 am[4][2] = {};
    #pragma unroll
    for (int ky = 0; ky < 3; ++ky) {
        int rb = ry + ky;                   // ring slot (0..3), no wrap needed
        ALOAD2(0, rb, 0);
        #pragma unroll
        for (int j = 0; j < 6; ++j) {
            int kt = ky * 6 + j;
            if (j < 5) ALOAD2((j + 1) & 1, rb, j + 1);
            __builtin_amdgcn_s_setprio(1);
            #pragma unroll
            for (int mi = 0; mi < 4; ++mi)
                #pragma unroll
                for (int ni = 0; ni < 2; ++ni)
                    am[mi][ni] = __builtin_amdgcn_mfma_f32_16x16x32_bf16(
                        abuf[j & 1][mi], bbuf[kt & 3][ni], am[mi][ni], 0, 0, 0);
            __builtin_amdgcn_s_setprio(0);
            if (kt + 4 < 18) BLOAD2(kt & 3, kt + 4);  // refill slot just consumed
        }
    }
    #undef STAGE2
    #undef ALOAD2
    #undef BLOAD2

    // ---- epilogue: BN+leaky+idn+leaky -> transpose via reused staging LDS ----
    __syncthreads();                        // all waves done reading row bufs
    float* tr = (float*)smem;               // [2 rows][64 px][stride 66 f32] = 33792 B
    #pragma unroll
    for (int ni = 0; ni < 2; ++ni) {
        int c = nh * 32 + ni * 16 + lr;
        float s  = sc[512 + c];
        float sh = sc[576 + c];
        #pragma unroll
        for (int mi = 0; mi < 4; ++mi) {
            #pragma unroll
            for (int r = 0; r < 4; ++r) {
                int xl = mi * 16 + lk * 4 + r;      // local px 0..63
                float v = am[mi][ni][r] * s + sh;
                v = (v >= 0.f) ? v : ALPHA * v;
                v = v + __bfloat162float(lds_idn[(xl >> 1) * 66 + c]);
                v = (v >= 0.f) ? v : ALPHA * v;
                tr[(ry * 64 + xl) * 66 + c] = v;
            }
        }
    }
    __syncthreads();
    // copy out: 2 rows x 64 px x 64 ch fp32, coalesced, NON-TEMPORAL
    #pragma unroll
    for (int it = 0; it < 8; ++it) {        // 8*256 = 2048 f32x4 = 32 KB
        int idx = it * 256 + threadIdx.x;
        int rr = idx >> 10;                 // row within pair
        int i = idx & 1023;
        int px = i >> 4, cq = i & 15;
        f32x4 v4 = *(const f32x4*)(tr + (rr * 64 + px) * 66 + cq * 4);
        float* orow = out + ((size_t)(n * H2 + Y0 + rr) * W2 + X0) * 64;
        __builtin_nontemporal_store(v4, (f32x4*)(orow + px * 64 + cq * 4));
    }
}

// ---------------- launcher ----------------

extern "C" void kernel_launch(void* const* d_in, const int* in_sizes, int n_in,
                              void* d_out, int out_size, void* d_ws, size_t ws_size,
                              hipStream_t stream) {
    const float* x   = (const float*)d_in[0];
    const float* W1  = (const float*)d_in[1];
    const float* b1  = (const float*)d_in[2];
    const float* g1  = (const float*)d_in[3];
    const float* be1 = (const float*)d_in[4];
    const float* m1  = (const float*)d_in[5];
    const float* v1  = (const float*)d_in[6];
    const float* W2  = (const float*)d_in[7];
    const float* b2  = (const float*)d_in[8];
    const float* g2  = (const float*)d_in[9];
    const float* be2 = (const float*)d_in[10];
    const float* m2  = (const float*)d_in[11];
    const float* v2  = (const float*)d_in[12];
    const float* Wu  = (const float*)d_in[13];
    const float* bu  = (const float*)d_in[14];
    float* out = (float*)d_out;

    char* ws = (char*)d_ws;
    __hip_bfloat16* xp  = (__hip_bfloat16*)(ws + OFF_XPAD);
    __hip_bfloat16* t1  = (__hip_bfloat16*)(ws + OFF_T1);
    __hip_bfloat16* pw1 = (__hip_bfloat16*)(ws + OFF_PW1);
    __hip_bfloat16* pw2 = (__hip_bfloat16*)(ws + OFF_PW2);
    float* sc = (float*)(ws + OFF_SC);

    pack_w<<<369, 64, 0, stream>>>(W1, W2, Wu, b1, g1, be1, m1, v1,
                                   b2, g2, be2, m2, v2, pw1, pw2, sc);
    prep_bufs<<<2048, 256, 0, stream>>>(x, xp, t1,
                                        B_ * HP * WP * 8, 16 * 1028 * 8);
    gemm1<<<4096, 256, 0, stream>>>(xp, pw1, sc, t1);
    gemm2<<<8192, 256, 0, stream>>>(t1, xp, pw2, sc, bu, out);
}

// Round 12
// 231.068 us; speedup vs baseline: 1.0690x; 1.0690x over previous
//
#include <hip/hip_runtime.h>
#include <hip/hip_bf16.h>

#define ALPHA 0.2f
#define EPS 1e-3f

typedef __bf16 bf16x8 __attribute__((ext_vector_type(8)));
typedef float f32x4 __attribute__((ext_vector_type(4)));

// problem dims
constexpr int B_  = 16;
constexpr int H_  = 128, W_ = 128;
constexpr int HP  = 130, WP = 130;    // padded x
constexpr int H2  = 256, W2 = 256;    // upsampled
constexpr int H2P = 258, W2P = 258;   // padded t1

// ws layout (bytes)
constexpr size_t OFF_XPAD = 0;                                   // bf16 [16][130][130][64]
constexpr size_t OFF_T1   = 34611200;                            // bf16 [16][258][258][64]
constexpr size_t OFF_PW1  = OFF_T1 + 136323072;                  // bf16 packed 576*256
constexpr size_t OFF_PW2  = OFF_PW1 + 294912;                    // bf16 packed 640*64
constexpr size_t OFF_SC   = OFF_PW2 + 81920;                     // f32 scale/shift

// async global->LDS, 16B per lane. LDS dest must be WAVE-UNIFORM (HW adds lane*16).
__device__ __forceinline__ void gload_lds16(const void* g, void* l) {
    __builtin_amdgcn_global_load_lds(
        (const __attribute__((address_space(1))) unsigned int*)g,
        (__attribute__((address_space(3))) unsigned int*)l, 16, 0, 0);
}

// ---------------- prep kernels ----------------

// pack weights in MFMA B-fragment order; block 368 computes BN scale/shift.
__global__ void pack_w(const float* W1f, const float* W2f, const float* Wuf,
                       const float* b1, const float* g1, const float* be1,
                       const float* m1, const float* v1,
                       const float* b2, const float* g2, const float* be2,
                       const float* m2, const float* v2,
                       __hip_bfloat16* pw1, __hip_bfloat16* pw2, float* sc) {
    int blk = blockIdx.x;
    int l = threadIdx.x;
    if (blk < 288) {
        int kt = blk / 16, nt = blk % 16;
        #pragma unroll
        for (int j = 0; j < 8; ++j) {
            int k = kt * 32 + (l >> 4) * 8 + j;
            int n = nt * 16 + (l & 15);
            pw1[blk * 512 + l * 8 + j] = __float2bfloat16(W1f[k * 256 + n]);
        }
    } else if (blk < 368) {
        int bi = blk - 288;
        int kt = bi / 4, nt = bi % 4;
        #pragma unroll
        for (int j = 0; j < 8; ++j) {
            int k = kt * 32 + (l >> 4) * 8 + j;
            int n = nt * 16 + (l & 15);
            float v = (k < 576) ? W2f[k * 64 + n] : Wuf[(k - 576) * 64 + n];
            pw2[bi * 512 + l * 8 + j] = __float2bfloat16(v);
        }
    } else {
        #pragma unroll
        for (int q = 0; q < 4; ++q) {
            int t = q * 64 + l;
            float s = g1[t] * rsqrtf(v1[t] + EPS);
            sc[t]       = s;
            sc[256 + t] = (b1[t] - m1[t]) * s + be1[t];
        }
        if (l < 64) {
            float s = g2[l] * rsqrtf(v2[l] + EPS);
            sc[512 + l] = s;
            sc[576 + l] = (b2[l] - m2[l]) * s + be2[l];
        }
    }
}

// fused: pad+cast x -> xp (vector bf16x8) AND zero t1 border
__global__ void prep_bufs(const float* x, __hip_bfloat16* xp,
                          __hip_bfloat16* t1, int total8, int totalb) {
    for (int e = blockIdx.x * blockDim.x + threadIdx.x; e < total8 + totalb;
         e += gridDim.x * blockDim.x) {
        if (e < total8) {
            int c8 = (e & 7) * 8;
            int t = e >> 3;
            int xx = t % WP; t /= WP;
            int yy = t % HP; t /= HP;
            int n = t;
            union { bf16x8 v; __hip_bfloat16 h[8]; } o;
            if (yy >= 1 && yy <= H_ && xx >= 1 && xx <= W_) {
                const float* src = x + ((size_t)(n * H_ + (yy - 1)) * W_ + (xx - 1)) * 64 + c8;
                float4 f0 = *(const float4*)src;
                float4 f1 = *(const float4*)(src + 4);
                o.h[0] = __float2bfloat16(f0.x); o.h[1] = __float2bfloat16(f0.y);
                o.h[2] = __float2bfloat16(f0.z); o.h[3] = __float2bfloat16(f0.w);
                o.h[4] = __float2bfloat16(f1.x); o.h[5] = __float2bfloat16(f1.y);
                o.h[6] = __float2bfloat16(f1.z); o.h[7] = __float2bfloat16(f1.w);
            } else {
                #pragma unroll
                for (int j = 0; j < 8; ++j) o.h[j] = __float2bfloat16(0.f);
            }
            *(bf16x8*)(xp + (size_t)e * 8) = o.v;
        } else {
            int eb = e - total8;            // border: 16*1028 sites x 8-ch groups
            int c8 = (eb & 7) * 8;
            int t = eb >> 3;
            int p = t % 1028;
            int n = t / 1028;
            int yy, xx;
            if (p < 258)      { yy = 0;   xx = p; }
            else if (p < 516) { yy = 257; xx = p - 258; }
            else { int p2 = p - 516; yy = 1 + (p2 >> 1); xx = (p2 & 1) ? 257 : 0; }
            union { bf16x8 v; __hip_bfloat16 h[8]; } z;
            #pragma unroll
            for (int j = 0; j < 8; ++j) z.h[j] = __float2bfloat16(0.f);
            *(bf16x8*)(t1 + ((size_t)(n * H2P + yy) * W2P + xx) * 64 + c8) = z.v;
        }
    }
}

// ---------------- GEMM1: conv1 + BN + leaky + subpixel ----------------
// R10 structure (dbuf LDS row staging, B ring-3, NO setprio — m190: setprio is
// null-to-negative on lockstep GEMM waves; R11 confirmed +11us regression).
__global__ __launch_bounds__(256, 3)
void gemm1(const __hip_bfloat16* xp, const __hip_bfloat16* pw1,
           const float* sc, __hip_bfloat16* t1) {
    __shared__ __hip_bfloat16 lds_a[2][4608];     // 2 x 9216 B (72 px each)
    __shared__ __hip_bfloat16 lds_t1[2 * 128 * 64]; // 32768 B

    int bid = blockIdx.x;
    int b = (bid & 7) * 512 + (bid >> 3);   // XCD-chunked swizzle (4096 = 8*512)
    int n = b >> 8;
    int y = (b >> 1) & 127;
    int x0 = (b & 1) * 64;
    int w = threadIdx.x >> 6;
    int l = threadIdx.x & 63;
    int lr = l & 15, lk = l >> 4;

    const __hip_bfloat16* Bbase = pw1 + (size_t)(w * 4) * 512 + l * 8;
    f32x4 acc[4][4] = {};
    bf16x8 abuf[2][4], bbuf[3][4];

    #define STAGE1(ky_, buf_) do {                                            \
        const char* rowg = (const char*)(xp +                                 \
            ((size_t)(n * HP + y + (ky_)) * WP + x0) * 64);                   \
        for (int j = w; j < 9; j += 4) {                                      \
            int off = j * 1024 + l * 16;                                      \
            int p = off >> 7, s2 = (off >> 4) & 7;                            \
            gload_lds16(rowg + (size_t)p * 128 + ((s2 ^ (p & 7)) << 4),       \
                        (char*)lds_a[buf_] + j * 1024);                       \
        } } while (0)

    #define ALOAD1(dst, buf_, j_) do {                                        \
        int kx = (j_) >> 1;                                                   \
        int o = ((j_) & 1) * 64 + lk * 16;                                    \
        _Pragma("unroll")                                                     \
        for (int mi = 0; mi < 4; ++mi) {                                      \
            int p = mi * 16 + lr + kx;                                        \
            abuf[dst][mi] = *(const bf16x8*)((const char*)lds_a[buf_] +       \
                p * 128 + (o ^ ((p & 7) << 4)));                              \
        } } while (0)

    #define BLOAD1(s_, kt_) do {                                              \
        const __hip_bfloat16* bp = Bbase + (size_t)(kt_) * 16 * 512;          \
        _Pragma("unroll")                                                     \
        for (int ni = 0; ni < 4; ++ni)                                        \
            bbuf[s_][ni] = *(const bf16x8*)(bp + ni * 512);                   \
        } while (0)

    STAGE1(0, 0);
    BLOAD1(0, 0);
    BLOAD1(1, 1);
    BLOAD1(2, 2);
    __syncthreads();

    #pragma unroll
    for (int ky = 0; ky < 3; ++ky) {
        if (ky < 2) STAGE1(ky + 1, (ky + 1) & 1);   // in flight during compute
        ALOAD1(0, ky & 1, 0);
        #pragma unroll
        for (int j = 0; j < 6; ++j) {
            int kt = ky * 6 + j;
            if (j < 5) ALOAD1((j + 1) & 1, ky & 1, j + 1);
            #pragma unroll
            for (int mi = 0; mi < 4; ++mi)
                #pragma unroll
                for (int ni = 0; ni < 4; ++ni)
                    acc[mi][ni] = __builtin_amdgcn_mfma_f32_16x16x32_bf16(
                        abuf[j & 1][mi], bbuf[kt % 3][ni], acc[mi][ni], 0, 0, 0);
            if (kt + 3 < 18) BLOAD1(kt % 3, kt + 3);  // refill slot just consumed
        }
        if (ky < 2) __syncthreads();
    }
    #undef STAGE1
    #undef ALOAD1
    #undef BLOAD1

    // epilogue: BN+leaky, subpixel transpose in LDS, coalesced store
    #pragma unroll
    for (int ni = 0; ni < 4; ++ni) {
        int c = w * 64 + ni * 16 + lr;
        float s  = sc[c];
        float sh = sc[256 + c];
        int g  = c >> 2;
        int hi = (c >> 1) & 1;
        int wi = c & 1;
        #pragma unroll
        for (int mi = 0; mi < 4; ++mi) {
            #pragma unroll
            for (int r = 0; r < 4; ++r) {
                int xl = mi * 16 + lk * 4 + r;
                float v = acc[mi][ni][r] * s + sh;
                v = (v >= 0.f) ? v : ALPHA * v;
                lds_t1[(wi * 128 + 2 * xl + hi) * 64 + g] = __float2bfloat16(v);
            }
        }
    }
    __syncthreads();
    #pragma unroll
    for (int wi_ = 0; wi_ < 2; ++wi_) {
        char* dst = (char*)(t1 + ((size_t)(n * H2P + 2 * y + wi_ + 1) * W2P
                                  + 2 * x0 + 1) * 64);
        const char* src = (const char*)lds_t1 + wi_ * 16384;
        #pragma unroll
        for (int it = 0; it < 4; ++it) {
            int off = it * 4096 + threadIdx.x * 16;
            *(float4*)(dst + off) = *(const float4*)(src + off);
        }
    }
}

// ---------------- GEMM2: conv2 + BN + leaky + residual ----------------
// R10 monolithic-stage structure (B ring-4, NT out stores, no setprio).
__global__ __launch_bounds__(256, 4)
void gemm2(const __hip_bfloat16* t1, const __hip_bfloat16* xp,
           const __hip_bfloat16* pw2, const float* sc, const float* bu,
           float* out) {
    __shared__ alignas(16) char smem[4 * 8448 + 4224];    // 4 row bufs + idn = 38016 B
    __hip_bfloat16* lds_idn = (__hip_bfloat16*)(smem + 4 * 8448);

    int bid = blockIdx.x;
    int b = (bid & 7) * 1024 + (bid >> 3);  // XCD-chunked swizzle (8192 = 8*1024)
    int n = b >> 9;
    int rem = b & 511;
    int Y0 = (rem >> 2) * 2;                // even output row pair
    int X0 = (rem & 3) * 64;
    int w = threadIdx.x >> 6;
    int l = threadIdx.x & 63;
    int lr = l & 15, lk = l >> 4;
    int ry = w >> 1;          // output row within pair
    int nh = w & 1;           // ni half: ch [nh*32, nh*32+32)

    bf16x8 abuf[2][4], bbuf[4][2];

    // stage input row r_ (padded t1 row Y0+r_), 66 px = 8448 B, into ring slot r_
    #define STAGE2(r_) do {                                                   \
        const char* rowg = (const char*)t1 +                                  \
            ((size_t)(n * H2P + Y0 + (r_)) * W2P + X0) * 128;                 \
        for (int j = w; j < 9; j += 4) {                                      \
            if (j < 8 || l < 16) {                                            \
                int off = j * 1024 + l * 16;                                  \
                int p = off >> 7, s2 = (off >> 4) & 7;                        \
                gload_lds16(rowg + (size_t)p * 128 + ((s2 ^ (p & 7)) << 4),   \
                            smem + (r_) * 8448 + j * 1024);                   \
            }                                                                 \
        } } while (0)

    #define ALOAD2(dst, rb_, j_) do {                                         \
        int kx = (j_) >> 1;                                                   \
        int o = ((j_) & 1) * 64 + lk * 16;                                    \
        _Pragma("unroll")                                                     \
        for (int mi = 0; mi < 4; ++mi) {                                      \
            int p = mi * 16 + lr + kx;                                        \
            abuf[dst][mi] = *(const bf16x8*)(smem + (rb_) * 8448 +            \
                p * 128 + (o ^ ((p & 7) << 4)));                              \
        } } while (0)

    #define BLOAD2(s_, kt_) do {                                              \
        const __hip_bfloat16* bp = pw2 +                                      \
            ((size_t)(kt_) * 4 + nh * 2) * 512 + l * 8;                       \
        _Pragma("unroll")                                                     \
        for (int ni = 0; ni < 2; ++ni)                                        \
            bbuf[s_][ni] = *(const bf16x8*)(bp + ni * 512);                   \
        } while (0)

    // ---- residual loads FIRST (oldest vmcnt slots; waves 0,1 only)
    bf16x8 pa[2], pb[2][4];
    if (w < 2) {
        #pragma unroll
        for (int kt2 = 0; kt2 < 2; ++kt2) {
            int ci0 = kt2 * 32 + lk * 8;
            int u = (X0 >> 1) + w * 16 + lr;        // low-res col (unpadded)
            pa[kt2] = *(const bf16x8*)(
                xp + ((size_t)(n * HP + (Y0 >> 1) + 1) * WP + u + 1) * 64 + ci0);
            const __hip_bfloat16* bp = pw2 + (size_t)((18 + kt2) * 4) * 512 + l * 8;
            #pragma unroll
            for (int ni = 0; ni < 4; ++ni)
                pb[kt2][ni] = *(const bf16x8*)(bp + ni * 512);
        }
    }
    STAGE2(0); STAGE2(1); STAGE2(2); STAGE2(3);
    BLOAD2(0, 0);
    BLOAD2(1, 1);
    BLOAD2(2, 2);
    BLOAD2(3, 3);

    // ---- residual 1x1 conv -> lds_idn (32 unique low-res px, shared by both rows)
    if (w < 2) {
        f32x4 aid[4] = {};
        #pragma unroll
        for (int kt2 = 0; kt2 < 2; ++kt2)
            #pragma unroll
            for (int ni = 0; ni < 4; ++ni)
                aid[ni] = __builtin_amdgcn_mfma_f32_16x16x32_bf16(
                    pa[kt2], pb[kt2][ni], aid[ni], 0, 0, 0);
        #pragma unroll
        for (int ni = 0; ni < 4; ++ni) {
            int c = ni * 16 + lr;
            float bc = bu[c];
            #pragma unroll
            for (int r = 0; r < 4; ++r) {
                int u = w * 16 + lk * 4 + r;         // local 0..31
                lds_idn[u * 66 + c] = __float2bfloat16(aid[ni][r] + bc);
            }
        }
    }
    __syncthreads();      // THE barrier: all 4 rows staged + idn ready

    // ---- barrier-free K-loop: 3 ky x 6 j x (4 mi x 2 ni) = 144 MFMAs/wave
    f32x4 am[4][2] = {};
    #pragma unroll
    for (int ky = 0; ky < 3; ++ky) {
        int rb = ry + ky;                   // ring slot (0..3), no wrap needed
        ALOAD2(0, rb, 0);
        #pragma unroll
        for (int j = 0; j < 6; ++j) {
            int kt = ky * 6 + j;
            if (j < 5) ALOAD2((j + 1) & 1, rb, j + 1);
            #pragma unroll
            for (int mi = 0; mi < 4; ++mi)
                #pragma unroll
                for (int ni = 0; ni < 2; ++ni)
                    am[mi][ni] = __builtin_amdgcn_mfma_f32_16x16x32_bf16(
                        abuf[j & 1][mi], bbuf[kt & 3][ni], am[mi][ni], 0, 0, 0);
            if (kt + 4 < 18) BLOAD2(kt & 3, kt + 4);  // refill slot just consumed
        }
    }
    #undef STAGE2
    #undef ALOAD2
    #undef BLOAD2

    // ---- epilogue: BN+leaky+idn+leaky -> transpose via reused staging LDS ----
    __syncthreads();                        // all waves done reading row bufs
    float* tr = (float*)smem;               // [2 rows][64 px][stride 66 f32] = 33792 B
    #pragma unroll
    for (int ni = 0; ni < 2; ++ni) {
        int c = nh * 32 + ni * 16 + lr;
        float s  = sc[512 + c];
        float sh = sc[576 + c];
        #pragma unroll
        for (int mi = 0; mi < 4; ++mi) {
            #pragma unroll
            for (int r = 0; r < 4; ++r) {
                int xl = mi * 16 + lk * 4 + r;      // local px 0..63
                float v = am[mi][ni][r] * s + sh;
                v = (v >= 0.f) ? v : ALPHA * v;
                v = v + __bfloat162float(lds_idn[(xl >> 1) * 66 + c]);
                v = (v >= 0.f) ? v : ALPHA * v;
                tr[(ry * 64 + xl) * 66 + c] = v;
            }
        }
    }
    __syncthreads();
    // copy out: 2 rows x 64 px x 64 ch fp32, coalesced, NON-TEMPORAL
    #pragma unroll
    for (int it = 0; it < 8; ++it) {        // 8*256 = 2048 f32x4 = 32 KB
        int idx = it * 256 + threadIdx.x;
        int rr = idx >> 10;                 // row within pair
        int i = idx & 1023;
        int px = i >> 4, cq = i & 15;
        f32x4 v4 = *(const f32x4*)(tr + (rr * 64 + px) * 66 + cq * 4);
        float* orow = out + ((size_t)(n * H2 + Y0 + rr) * W2 + X0) * 64;
        __builtin_nontemporal_store(v4, (f32x4*)(orow + px * 64 + cq * 4));
    }
}

// ---------------- launcher ----------------

extern "C" void kernel_launch(void* const* d_in, const int* in_sizes, int n_in,
                              void* d_out, int out_size, void* d_ws, size_t ws_size,
                              hipStream_t stream) {
    const float* x   = (const float*)d_in[0];
    const float* W1  = (const float*)d_in[1];
    const float* b1  = (const float*)d_in[2];
    const float* g1  = (const float*)d_in[3];
    const float* be1 = (const float*)d_in[4];
    const float* m1  = (const float*)d_in[5];
    const float* v1  = (const float*)d_in[6];
    const float* W2  = (const float*)d_in[7];
    const float* b2  = (const float*)d_in[8];
    const float* g2  = (const float*)d_in[9];
    const float* be2 = (const float*)d_in[10];
    const float* m2  = (const float*)d_in[11];
    const float* v2  = (const float*)d_in[12];
    const float* Wu  = (const float*)d_in[13];
    const float* bu  = (const float*)d_in[14];
    float* out = (float*)d_out;

    char* ws = (char*)d_ws;
    __hip_bfloat16* xp  = (__hip_bfloat16*)(ws + OFF_XPAD);
    __hip_bfloat16* t1  = (__hip_bfloat16*)(ws + OFF_T1);
    __hip_bfloat16* pw1 = (__hip_bfloat16*)(ws + OFF_PW1);
    __hip_bfloat16* pw2 = (__hip_bfloat16*)(ws + OFF_PW2);
    float* sc = (float*)(ws + OFF_SC);

    pack_w<<<369, 64, 0, stream>>>(W1, W2, Wu, b1, g1, be1, m1, v1,
                                   b2, g2, be2, m2, v2, pw1, pw2, sc);
    prep_bufs<<<2048, 256, 0, stream>>>(x, xp, t1,
                                        B_ * HP * WP * 8, 16 * 1028 * 8);
    gemm1<<<4096, 256, 0, stream>>>(xp, pw1, sc, t1);
    gemm2<<<8192, 256, 0, stream>>>(t1, xp, pw2, sc, bu, out);
}